// Round 15
// baseline (76.034 us; speedup 1.0000x reference)
//
#include <hip/hip_runtime.h>

#define HW   16384
#define WID  128
#define HEI  128
#define CIN  64
#define OCH  64

typedef __attribute__((ext_vector_type(8))) short bf16x8;
typedef __attribute__((ext_vector_type(4))) short bf16x4;
typedef __attribute__((ext_vector_type(4))) float f32x4;

__device__ __forceinline__ unsigned short f2bf(float f) {
    unsigned u = __float_as_uint(f);
    u += 0x7FFF + ((u >> 16) & 1);          // RNE
    return (unsigned short)(u >> 16);
}
__device__ __forceinline__ float bf2f(short s) {
    return __uint_as_float(((unsigned)(unsigned short)s) << 16);
}

// ---------------- kernel P: x transpose + weight pack ----------------------
// blocks 0..255:   x NCHW f32 -> NHWC bf16
// blocks 256..471: pack w_dcn (36864) and w_off (18432) into B-fragment order
__global__ __launch_bounds__(256) void kprep(const float* __restrict__ x,
                                             const float* __restrict__ wdcn,
                                             const float* __restrict__ woff,
                                             unsigned short* __restrict__ xt,
                                             unsigned short* __restrict__ wpack,
                                             unsigned short* __restrict__ woffpack) {
    int blk = blockIdx.x;
    if (blk < 256) {
        int gp = blk * 256 + threadIdx.x;      // 0..65535 = (b, hw)
        int b = gp >> 14;
        int hw = gp & (HW - 1);
        const float* xb = x + (size_t)b * CIN * HW + hw;
        unsigned short* o = xt + ((size_t)gp << 6);
#pragma unroll
        for (int c8 = 0; c8 < 8; c8++) {
            bf16x8 v;
#pragma unroll
            for (int j = 0; j < 8; j++)
                v[j] = (short)f2bf(xb[(size_t)(c8 * 8 + j) * HW]);
            *(bf16x8*)(o + c8 * 8) = v;
        }
    } else {
        int t = (blk - 256) * 256 + threadIdx.x;   // 0..55295
        if (t < 36864) {
            int j  = t & 7;
            int l  = (t >> 3) & 63;
            int nt = (t >> 9) & 3;
            int s  = t >> 11;                      // 0..17
            int k  = s * 32 + (l >> 4) * 8 + j;
            int o  = nt * 16 + (l & 15);
            int tap = k >> 6, c = k & 63;
            wpack[t] = f2bf(wdcn[o * 576 + c * 9 + tap]);
        } else {
            int u  = t - 36864;                    // 0..18431
            int j  = u & 7;
            int l  = (u >> 3) & 63;
            int nt = (u >> 9) & 1;
            int s  = u >> 10;                      // 0..17
            int k  = s * 32 + (l >> 4) * 8 + j;
            int o  = nt * 16 + (l & 15);
            int tap = k >> 6, c = k & 63;
            float v = (o < 18) ? woff[o * 576 + c * 9 + tap] : 0.f;
            woffpack[u] = f2bf(v);
        }
    }
}

// ---------------- kernel B: wave-independent DCN (NO __syncthreads) --------
// Each wave owns 16 consecutive-w pixels and the full 64-channel output.
// A-fragments are gathered per-lane directly from NHWC xt (lane = (px, hi)
// loads its own 16B channel-octet per corner) — no patch LDS at all.
// Offsets flow through a 1.2KB wave-private LDS slab (same-wave lgkmcnt).
__global__ __launch_bounds__(256) void kdcn(const unsigned short* __restrict__ xt,
                                            const unsigned short* __restrict__ wpack,
                                            const unsigned short* __restrict__ woffpack,
                                            const float* __restrict__ boff,
                                            const float* __restrict__ bdcn,
                                            unsigned short* __restrict__ convb,
                                            float* __restrict__ part) {
    __shared__ float offLds[4][288];            // [wave][16 px * 18 oc]

    int tid = threadIdx.x;
    int lane = tid & 63, wave = tid >> 6;
    int lr = lane & 15, hi = lane >> 4;

    int gw = blockIdx.x * 4 + wave;             // global wave id, 0..4095
    int pixg = gw << 4;
    int b = pixg >> 14;
    int hwb = pixg & (HW - 1);
    int h = hwb >> 7;                           // 16 | 128 -> single row
    int w0 = hwb & (WID - 1);
    int px = lr;
    int w = w0 + px;

    const unsigned char* xtb =
        (const unsigned char*)xt + (((size_t)b * HW) << 7) + hi * 16;

    // ---- offset conv via MFMA: D[16 px][18 oc] --------------------------
    f32x4 oacc0, oacc1;
    {
        float ob0 = boff[lr];
        float ob1 = (lr < 2) ? boff[16 + lr] : 0.f;
        oacc0 = f32x4{ob0, ob0, ob0, ob0};
        oacc1 = f32x4{ob1, ob1, ob1, ob1};
    }
#pragma unroll
    for (int s = 0; s < 18; s++) {
        int tap = s >> 1;
        int sy = h + tap / 3 - 1;
        int sx = w + tap % 3 - 1;
        bool ok = ((unsigned)sy < HEI) && ((unsigned)sx < WID);
        bf16x8 a = {0, 0, 0, 0, 0, 0, 0, 0};
        if (ok) a = *(const bf16x8*)(xtb + ((sy * WID + sx) << 7) + (s & 1) * 64);
        bf16x8 b0 = *(const bf16x8*)(woffpack + s * 1024 + lane * 8);
        bf16x8 b1 = *(const bf16x8*)(woffpack + s * 1024 + 512 + lane * 8);
        oacc0 = __builtin_amdgcn_mfma_f32_16x16x32_bf16(a, b0, oacc0, 0, 0, 0);
        oacc1 = __builtin_amdgcn_mfma_f32_16x16x32_bf16(a, b1, oacc1, 0, 0, 0);
    }
    // redistribute within the wave (C layout: row px = hi*4+r, col oc = nt*16+lr)
    float* oL = offLds[wave];
#pragma unroll
    for (int r = 0; r < 4; r++) {
        oL[(hi * 4 + r) * 18 + lr] = oacc0[r];
        if (lr < 2) oL[(hi * 4 + r) * 18 + 16 + lr] = oacc1[r];
    }
    // (compiler orders ds_read after ds_write via lgkmcnt — same wave only)

    // ---- main accumulators: D[16 px][64 o], 4 o-tiles -------------------
    f32x4 acc[4];
#pragma unroll
    for (int nt = 0; nt < 4; nt++) {
        float bv = bdcn[nt * 16 + lr];
        acc[nt] = f32x4{bv, bv, bv, bv};
    }

#pragma unroll
    for (int tap = 0; tap < 9; tap++) {
        float dy = oL[px * 18 + 2 * tap];
        float dx = oL[px * 18 + 2 * tap + 1];
        float py  = dy + (float)(h + tap / 3 - 1);
        float pxf = dx + (float)(w + tap % 3 - 1);
        float y0f = floorf(py), x0f = floorf(pxf);
        float wy = py - y0f, wx = pxf - x0f;
        int y0 = (int)y0f, x0 = (int)x0f;
        float wy0 = ((unsigned)y0       < HEI) ? 1.f - wy : 0.f;
        float wy1 = ((unsigned)(y0 + 1) < HEI) ? wy       : 0.f;
        float wx0 = ((unsigned)x0       < WID) ? 1.f - wx : 0.f;
        float wx1 = ((unsigned)(x0 + 1) < WID) ? wx       : 0.f;
        int yc0 = min(max(y0, 0),     HEI - 1) * WID;
        int yc1 = min(max(y0 + 1, 0), HEI - 1) * WID;
        int xc0 = min(max(x0, 0),     WID - 1);
        int xc1 = min(max(x0 + 1, 0), WID - 1);
        float w00 = wy0 * wx0, w01 = wy0 * wx1;
        float w10 = wy1 * wx0, w11 = wy1 * wx1;
        int b00 = (yc0 + xc0) << 7, b01 = (yc0 + xc1) << 7;
        int b10 = (yc1 + xc0) << 7, b11 = (yc1 + xc1) << 7;
        // s even octet (channels (hi*8)+j) and s odd octet (+64B)
        bf16x8 c00a = *(const bf16x8*)(xtb + b00);
        bf16x8 c01a = *(const bf16x8*)(xtb + b01);
        bf16x8 c10a = *(const bf16x8*)(xtb + b10);
        bf16x8 c11a = *(const bf16x8*)(xtb + b11);
        bf16x8 c00b = *(const bf16x8*)(xtb + b00 + 64);
        bf16x8 c01b = *(const bf16x8*)(xtb + b01 + 64);
        bf16x8 c10b = *(const bf16x8*)(xtb + b10 + 64);
        bf16x8 c11b = *(const bf16x8*)(xtb + b11 + 64);
        bf16x8 a0, a1;
#pragma unroll
        for (int j = 0; j < 8; j++) {
            float sa = w00 * bf2f(c00a[j]) + w01 * bf2f(c01a[j])
                     + w10 * bf2f(c10a[j]) + w11 * bf2f(c11a[j]);
            float sb = w00 * bf2f(c00b[j]) + w01 * bf2f(c01b[j])
                     + w10 * bf2f(c10b[j]) + w11 * bf2f(c11b[j]);
            a0[j] = (short)f2bf(sa);
            a1[j] = (short)f2bf(sb);
        }
        int s0 = 2 * tap, s1 = 2 * tap + 1;
#pragma unroll
        for (int nt = 0; nt < 4; nt++) {
            bf16x8 bf0 = *(const bf16x8*)(wpack + s0 * 2048 + nt * 512 + lane * 8);
            bf16x8 bf1 = *(const bf16x8*)(wpack + s1 * 2048 + nt * 512 + lane * 8);
            acc[nt] = __builtin_amdgcn_mfma_f32_16x16x32_bf16(a0, bf0, acc[nt], 0, 0, 0);
            acc[nt] = __builtin_amdgcn_mfma_f32_16x16x32_bf16(a1, bf1, acc[nt], 0, 0, 0);
        }
    }

    // ---- direct C stores (bf16): lane holds px = hi*4..+3 of o = nt*16+lr
#pragma unroll
    for (int nt = 0; nt < 4; nt++) {
        int o = nt * 16 + lr;
        unsigned short* cb = convb + ((size_t)b * OCH + o) * HW + hwb + hi * 4;
        bf16x4 v;
#pragma unroll
        for (int r = 0; r < 4; r++) v[r] = (short)f2bf(acc[nt][r]);
        *(bf16x4*)cb = v;
    }

    // ---- BN partials: per-wave sums over 16 px, plain stores -------------
#pragma unroll
    for (int nt = 0; nt < 4; nt++) {
        float s  = acc[nt][0] + acc[nt][1] + acc[nt][2] + acc[nt][3];
        float s2 = acc[nt][0]*acc[nt][0] + acc[nt][1]*acc[nt][1]
                 + acc[nt][2]*acc[nt][2] + acc[nt][3]*acc[nt][3];
        s  += __shfl_xor(s, 16);  s2 += __shfl_xor(s2, 16);
        s  += __shfl_xor(s, 32);  s2 += __shfl_xor(s2, 32);
        if (hi == 0) {
            int c = nt * 16 + lr;
            part[(size_t)c * 4096 + gw]        = s;
            part[(size_t)(64 + c) * 4096 + gw] = s2;
        }
    }
}

// ---------------- kernel R: reduce partials -> stats[128] ------------------
__global__ __launch_bounds__(256) void kred(const float* __restrict__ part,
                                            float* __restrict__ stats) {
    int row = blockIdx.x;                 // 0..127
    int tid = threadIdx.x;
    const float* p = part + (size_t)row * 4096;
    float s = 0.f;
#pragma unroll
    for (int i = 0; i < 16; i++) s += p[tid + i * 256];
#pragma unroll
    for (int d = 1; d < 64; d <<= 1) s += __shfl_xor(s, d);
    __shared__ float red[4];
    if ((tid & 63) == 0) red[tid >> 6] = s;
    __syncthreads();
    if (tid == 0) stats[row] = red[0] + red[1] + red[2] + red[3];
}

// ---------------- kernel D: finalize stats + normalize + relu --------------
__global__ __launch_bounds__(256) void kapply(const unsigned short* __restrict__ convb,
                                              float* __restrict__ out,
                                              const float* __restrict__ stats,
                                              const float* __restrict__ gamma,
                                              const float* __restrict__ beta) {
    int t = blockIdx.x * 256 + threadIdx.x;   // < 1048576 groups of 4
    int c = (t >> 12) & 63;
    float mean = stats[c] * (1.f / 65536.f);
    float var  = stats[64 + c] * (1.f / 65536.f) - mean * mean;
    float rstd = rsqrtf(var + 1e-5f);
    float sc = rstd * gamma[c];
    float sh = beta[c] - mean * sc;
    bf16x4 v = *(const bf16x4*)(convb + (size_t)t * 4);
    float4 r;
    r.x = fmaxf(bf2f(v[0]) * sc + sh, 0.f);
    r.y = fmaxf(bf2f(v[1]) * sc + sh, 0.f);
    r.z = fmaxf(bf2f(v[2]) * sc + sh, 0.f);
    r.w = fmaxf(bf2f(v[3]) * sc + sh, 0.f);
    ((float4*)out)[t] = r;
}

// ---------------- launch ---------------------------------------------------
extern "C" void kernel_launch(void* const* d_in, const int* in_sizes, int n_in,
                              void* d_out, int out_size, void* d_ws, size_t ws_size,
                              hipStream_t stream) {
    const float* x     = (const float*)d_in[0];
    const float* woff  = (const float*)d_in[1];
    const float* boff  = (const float*)d_in[2];
    const float* wdcn  = (const float*)d_in[3];
    const float* bdcn  = (const float*)d_in[4];
    const float* gamma = (const float*)d_in[5];
    const float* beta  = (const float*)d_in[6];
    float* out = (float*)d_out;

    // ws layout (bytes): xt 8MB | wpack 72KB | woffpack 36KB | part 2MB |
    //                    stats 512B | convb 8MB
    unsigned char* ws = (unsigned char*)d_ws;
    unsigned short* xt       = (unsigned short*)ws;             // 4,194,304 ush
    unsigned short* wpack    = (unsigned short*)(ws + 8388608); //    36,864 ush
    unsigned short* woffpack = (unsigned short*)(ws + 8462336); //    18,432 ush
    float*          part     = (float*)(ws + 8499200);          //   524,288 f
    float*          stats    = (float*)(ws + 10596352);         //       128 f
    unsigned short* convb    = (unsigned short*)(ws + 10596864);// 4,194,304 ush

    hipLaunchKernelGGL(kprep,  dim3(472),  dim3(256), 0, stream,
                       x, wdcn, woff, xt, wpack, woffpack);
    hipLaunchKernelGGL(kdcn,   dim3(1024), dim3(256), 0, stream,
                       xt, wpack, woffpack, boff, bdcn, convb, part);
    hipLaunchKernelGGL(kred,   dim3(128),  dim3(256), 0, stream, part, stats);
    hipLaunchKernelGGL(kapply, dim3(4096), dim3(256), 0, stream,
                       convb, out, stats, gamma, beta);
}

// Round 16
// 51.662 us; speedup vs baseline: 1.4718x; 1.4718x over previous
//
#include <hip/hip_runtime.h>

#define HW   16384
#define WID  128
#define HEI  128
#define CIN  64
#define OCH  64

typedef __attribute__((ext_vector_type(8))) short bf16x8;
typedef __attribute__((ext_vector_type(4))) short bf16x4;
typedef __attribute__((ext_vector_type(4))) float f32x4;

__device__ __forceinline__ unsigned short f2bf(float f) {
    unsigned u = __float_as_uint(f);
    u += 0x7FFF + ((u >> 16) & 1);          // RNE
    return (unsigned short)(u >> 16);
}
__device__ __forceinline__ float bf2f(short s) {
    return __uint_as_float(((unsigned)(unsigned short)s) << 16);
}

// ---------------- kernel P: x transpose + weight pack ----------------------
// blocks 0..255:   x NCHW f32 -> NHWC bf16
// blocks 256..471: pack w_dcn (36864) and w_off (18432) into B-fragment order
__global__ __launch_bounds__(256) void kprep(const float* __restrict__ x,
                                             const float* __restrict__ wdcn,
                                             const float* __restrict__ woff,
                                             unsigned short* __restrict__ xt,
                                             unsigned short* __restrict__ wpack,
                                             unsigned short* __restrict__ woffpack) {
    int blk = blockIdx.x;
    if (blk < 256) {
        int gp = blk * 256 + threadIdx.x;      // 0..65535 = (b, hw)
        int b = gp >> 14;
        int hw = gp & (HW - 1);
        const float* xb = x + (size_t)b * CIN * HW + hw;
        unsigned short* o = xt + ((size_t)gp << 6);
#pragma unroll
        for (int c8 = 0; c8 < 8; c8++) {
            bf16x8 v;
#pragma unroll
            for (int j = 0; j < 8; j++)
                v[j] = (short)f2bf(xb[(size_t)(c8 * 8 + j) * HW]);
            *(bf16x8*)(o + c8 * 8) = v;
        }
    } else {
        int t = (blk - 256) * 256 + threadIdx.x;   // 0..55295
        if (t < 36864) {
            int j  = t & 7;
            int l  = (t >> 3) & 63;
            int nt = (t >> 9) & 3;
            int s  = t >> 11;                      // 0..17
            int k  = s * 32 + (l >> 4) * 8 + j;
            int o  = nt * 16 + (l & 15);
            int tap = k >> 6, c = k & 63;
            wpack[t] = f2bf(wdcn[o * 576 + c * 9 + tap]);
        } else {
            int u  = t - 36864;                    // 0..18431
            int j  = u & 7;
            int l  = (u >> 3) & 63;
            int nt = (u >> 9) & 1;
            int s  = u >> 10;                      // 0..17
            int k  = s * 32 + (l >> 4) * 8 + j;
            int o  = nt * 16 + (l & 15);
            int tap = k >> 6, c = k & 63;
            float v = (o < 18) ? woff[o * 576 + c * 9 + tap] : 0.f;
            woffpack[u] = f2bf(v);
        }
    }
}

// ---------------- kernel B: offset conv + deformable sample + MFMA ---------
// block = 4 waves, 32 consecutive-w pixels.  3 barriers.
// LDS (39168 B -> 4 blocks/CU):
//   [0..36863]     phase 0/0b: 3x34 window (13056 B, XOR-swz by col);
//                  phase B/MFMA: patch bf16 [32 px][576 k] pitch 1152 B,
//                  XOR-swizzled by (px&7)<<4 (overwrites the dead window)
//   [36864..39167] offLds f32 [32 px][18]
__global__ __launch_bounds__(256, 4) void kdcn(const unsigned short* __restrict__ xt,
                                               const unsigned short* __restrict__ wpack,
                                               const unsigned short* __restrict__ woffpack,
                                               const float* __restrict__ boff,
                                               const float* __restrict__ bdcn,
                                               unsigned short* __restrict__ convb,
                                               float* __restrict__ part) {
    __shared__ __align__(16) unsigned char smem[39168];

    int tid = threadIdx.x;
    int lane = tid & 63, wave = tid >> 6;
    int lr = lane & 15, hi = lane >> 4;

    int pixg = blockIdx.x * 32;
    int b = pixg >> 14;                 // uniform
    int hwb = pixg & (HW - 1);
    int h = hwb >> 7;                   // uniform (32 | 128)
    int w0 = hwb & (WID - 1);

    // ---- phase 0: stage 3x34-col window (zero-padded) into LDS ------------
    // rows h-1..h+1, cols w0-1..w0+32; 102 cells x 8 sub-chunks = 816 loads
    {
        const unsigned char* xb = (const unsigned char*)xt + (((size_t)b * HW) << 7);
#pragma unroll
        for (int i = 0; i < 4; i++) {
            int item = tid + i * 256;
            if (item < 816) {
                int sub  = item & 7;
                int cell = item >> 3;          // 0..101
                int colw = cell % 34;
                int roww = cell / 34;
                int sy = h + roww - 1;
                int sx = w0 + colw - 1;
                bool ok = ((unsigned)sy < HEI) && ((unsigned)sx < WID);
                bf16x8 v = {0, 0, 0, 0, 0, 0, 0, 0};
                if (ok) v = *(const bf16x8*)(xb + ((sy * WID + sx) << 7) + sub * 16);
                *(bf16x8*)(smem + ((unsigned)((roww * 34 + colw) * 128 + sub * 16)
                                   ^ ((unsigned)(colw & 7) << 4))) = v;
            }
        }
    }
    __syncthreads();

    // ---- phase 0b: offset conv via MFMA; D[32 px][18 oc] -> offLds --------
    {
        int mw = wave & 1, nw = wave >> 1;
        int pxr = mw * 16 + lr;                // A-row pixel
        int oc = nw * 16 + lr;
        float ob = (oc < 18) ? boff[oc] : 0.f;
        f32x4 oacc = {ob, ob, ob, ob};
        const unsigned short* wop = woffpack + (size_t)(nw * 64 + lane) * 8;
#pragma unroll
        for (int s = 0; s < 18; s++) {
            int tap = s >> 1;
            int ky = tap / 3;
            int kx = tap - ky * 3;
            int colw = pxr + kx;
            unsigned addr = (unsigned)((ky * 34 + colw) * 128 + (s & 1) * 64 + hi * 16)
                          ^ ((unsigned)(colw & 7) << 4);
            bf16x8 a  = *(const bf16x8*)(smem + addr);
            bf16x8 wf = *(const bf16x8*)(wop + (size_t)s * 1024);
            oacc = __builtin_amdgcn_mfma_f32_16x16x32_bf16(a, wf, oacc, 0, 0, 0);
        }
        float* offLds = (float*)(smem + 36864);
        if (oc < 18) {
#pragma unroll
            for (int r = 0; r < 4; r++)
                offLds[(mw * 16 + hi * 4 + r) * 18 + oc] = oacc[r];
        }
    }

    // ---- B fragments + bias (o = wave*16 + lr) — load while 0b drains
    bf16x8 bfrag[18];
    const unsigned short* wp = wpack + (size_t)(wave * 64 + lane) * 8;
#pragma unroll
    for (int s = 0; s < 18; s++)
        bfrag[s] = *(const bf16x8*)(wp + (size_t)s * 2048);
    float bias = bdcn[wave * 16 + lr];
    __syncthreads();

    // ---- phase B: per-lane tap info + gather + interp + pack into patch ---
    {
        int g = lane >> 3, sub = lane & 7;
        int px = wave * 8 + g;
        int w = w0 + px;
        const unsigned char* xtb =
            (const unsigned char*)xt + (((size_t)b * HW) << 7) + sub * 16;
        unsigned char* prow = smem + px * 1152;
        unsigned swz = (unsigned)((px & 7) << 4);
        const float* offL = (const float*)(smem + 36864) + px * 18;
#pragma unroll
        for (int tap = 0; tap < 9; tap++) {
            float dy = offL[tap * 2];
            float dx = offL[tap * 2 + 1];
            float py  = dy + (float)(h + tap / 3 - 1);
            float pxf = dx + (float)(w + tap % 3 - 1);
            float y0f = floorf(py), x0f = floorf(pxf);
            float wy = py - y0f, wx = pxf - x0f;
            int y0 = (int)y0f, x0 = (int)x0f;
            float wy0 = ((unsigned)y0       < HEI) ? 1.f - wy : 0.f;
            float wy1 = ((unsigned)(y0 + 1) < HEI) ? wy       : 0.f;
            float wx0 = ((unsigned)x0       < WID) ? 1.f - wx : 0.f;
            float wx1 = ((unsigned)(x0 + 1) < WID) ? wx       : 0.f;
            int yc0 = min(max(y0, 0),     HEI - 1) * WID;
            int yc1 = min(max(y0 + 1, 0), HEI - 1) * WID;
            int xc0 = min(max(x0, 0),     WID - 1);
            int xc1 = min(max(x0 + 1, 0), WID - 1);
            float w00 = wy0 * wx0, w01 = wy0 * wx1;
            float w10 = wy1 * wx0, w11 = wy1 * wx1;
            bf16x8 c00 = *(const bf16x8*)(xtb + ((yc0 + xc0) << 7));
            bf16x8 c01 = *(const bf16x8*)(xtb + ((yc0 + xc1) << 7));
            bf16x8 c10 = *(const bf16x8*)(xtb + ((yc1 + xc0) << 7));
            bf16x8 c11 = *(const bf16x8*)(xtb + ((yc1 + xc1) << 7));
            bf16x8 v;
#pragma unroll
            for (int j = 0; j < 8; j++) {
                float sv = w00 * bf2f(c00[j]) + w01 * bf2f(c01[j])
                         + w10 * bf2f(c10[j]) + w11 * bf2f(c11[j]);
                v[j] = (short)f2bf(sv);
            }
            *(bf16x8*)(prow + ((unsigned)(tap * 128 + sub * 16) ^ swz)) = v;
        }
    }
    __syncthreads();

    // ---- main MFMA: D[32 px][64 o], wave owns o-tile = wave
    f32x4 acc0 = {bias, bias, bias, bias};
    f32x4 acc1 = acc0;
    unsigned swzr = (unsigned)((lr & 7) << 4);
#pragma unroll
    for (int s = 0; s < 18; s++) {
        unsigned inblk = (unsigned)((s >> 1) * 128)
                       + (((unsigned)((s & 1) * 64 + hi * 16)) ^ swzr);
        bf16x8 a0 = *(const bf16x8*)(smem + lr * 1152 + inblk);
        bf16x8 a1 = *(const bf16x8*)(smem + (16 + lr) * 1152 + inblk);
        acc0 = __builtin_amdgcn_mfma_f32_16x16x32_bf16(a0, bfrag[s], acc0, 0, 0, 0);
        acc1 = __builtin_amdgcn_mfma_f32_16x16x32_bf16(a1, bfrag[s], acc1, 0, 0, 0);
    }

    // ---- direct C stores (bf16): lane holds px = hi*4..+3 of o = wave*16+lr
    {
        int o = wave * 16 + lr;
        unsigned short* cb = convb + ((size_t)b * OCH + o) * HW + hwb + hi * 4;
        bf16x4 v0, v1;
#pragma unroll
        for (int r = 0; r < 4; r++) { v0[r] = (short)f2bf(acc0[r]);
                                      v1[r] = (short)f2bf(acc1[r]); }
        *(bf16x4*)cb        = v0;
        *(bf16x4*)(cb + 16) = v1;
    }

    // ---- BN partials (no barrier follows; plain stores, no contention) ----
    {
        float s  = acc0[0] + acc0[1] + acc0[2] + acc0[3]
                 + acc1[0] + acc1[1] + acc1[2] + acc1[3];
        float s2 = acc0[0]*acc0[0] + acc0[1]*acc0[1] + acc0[2]*acc0[2] + acc0[3]*acc0[3]
                 + acc1[0]*acc1[0] + acc1[1]*acc1[1] + acc1[2]*acc1[2] + acc1[3]*acc1[3];
        s  += __shfl_xor(s, 16);  s2 += __shfl_xor(s2, 16);
        s  += __shfl_xor(s, 32);  s2 += __shfl_xor(s2, 32);
        if (hi == 0) {
            int c = wave * 16 + lr;
            part[(size_t)c * 2048 + blockIdx.x]        = s;
            part[(size_t)(64 + c) * 2048 + blockIdx.x] = s2;
        }
    }
}

// ---------------- kernel R: reduce partials -> stats[128] ------------------
__global__ __launch_bounds__(256) void kred(const float* __restrict__ part,
                                            float* __restrict__ stats) {
    int row = blockIdx.x;                 // 0..127
    int tid = threadIdx.x;
    const float* p = part + (size_t)row * 2048;
    float s = 0.f;
#pragma unroll
    for (int i = 0; i < 8; i++) s += p[tid + i * 256];
#pragma unroll
    for (int d = 1; d < 64; d <<= 1) s += __shfl_xor(s, d);
    __shared__ float red[4];
    if ((tid & 63) == 0) red[tid >> 6] = s;
    __syncthreads();
    if (tid == 0) stats[row] = red[0] + red[1] + red[2] + red[3];
}

// ---------------- kernel D: finalize stats + normalize + relu --------------
__global__ __launch_bounds__(256) void kapply(const unsigned short* __restrict__ convb,
                                              float* __restrict__ out,
                                              const float* __restrict__ stats,
                                              const float* __restrict__ gamma,
                                              const float* __restrict__ beta) {
    int t = blockIdx.x * 256 + threadIdx.x;   // < 1048576 groups of 4
    int c = (t >> 12) & 63;
    float mean = stats[c] * (1.f / 65536.f);
    float var  = stats[64 + c] * (1.f / 65536.f) - mean * mean;
    float rstd = rsqrtf(var + 1e-5f);
    float sc = rstd * gamma[c];
    float sh = beta[c] - mean * sc;
    bf16x4 v = *(const bf16x4*)(convb + (size_t)t * 4);
    float4 r;
    r.x = fmaxf(bf2f(v[0]) * sc + sh, 0.f);
    r.y = fmaxf(bf2f(v[1]) * sc + sh, 0.f);
    r.z = fmaxf(bf2f(v[2]) * sc + sh, 0.f);
    r.w = fmaxf(bf2f(v[3]) * sc + sh, 0.f);
    ((float4*)out)[t] = r;
}

// ---------------- launch ---------------------------------------------------
extern "C" void kernel_launch(void* const* d_in, const int* in_sizes, int n_in,
                              void* d_out, int out_size, void* d_ws, size_t ws_size,
                              hipStream_t stream) {
    const float* x     = (const float*)d_in[0];
    const float* woff  = (const float*)d_in[1];
    const float* boff  = (const float*)d_in[2];
    const float* wdcn  = (const float*)d_in[3];
    const float* bdcn  = (const float*)d_in[4];
    const float* gamma = (const float*)d_in[5];
    const float* beta  = (const float*)d_in[6];
    float* out = (float*)d_out;

    // ws layout (bytes): xt 8MB | wpack 72KB | woffpack 36KB | part 1MB |
    //                    stats 512B | convb 8MB
    unsigned char* ws = (unsigned char*)d_ws;
    unsigned short* xt       = (unsigned short*)ws;            // 4,194,304 ush
    unsigned short* wpack    = (unsigned short*)(ws + 8388608);//    36,864 ush
    unsigned short* woffpack = (unsigned short*)(ws + 8462336);//    18,432 ush
    float*          part     = (float*)(ws + 8499200);         //   262,144 f
    float*          stats    = (float*)(ws + 9547776);         //       128 f
    unsigned short* convb    = (unsigned short*)(ws + 9548288);// 4,194,304 ush

    hipLaunchKernelGGL(kprep,  dim3(472),  dim3(256), 0, stream,
                       x, wdcn, woff, xt, wpack, woffpack);
    hipLaunchKernelGGL(kdcn,   dim3(2048), dim3(256), 0, stream,
                       xt, wpack, woffpack, boff, bdcn, convb, part);
    hipLaunchKernelGGL(kred,   dim3(128),  dim3(256), 0, stream, part, stats);
    hipLaunchKernelGGL(kapply, dim3(4096), dim3(256), 0, stream,
                       convb, out, stats, gamma, beta);
}